// Round 1
// baseline (927.020 us; speedup 1.0000x reference)
//
#include <hip/hip_runtime.h>

// GCN 2-layer: N=50000 nodes, E=800000 edges, 256 -> 128 (relu) -> 64
// Reference: deg = indeg(dst)+1 (self loops), dinv = rsqrt(deg),
//   h  = relu( scatter(norm * (x@W1)) + dinv^2*(x@W1) + b1 )
//   out =      scatter(norm * (h@W2)) + dinv^2*(h@W2) + b2
// where norm_e = dinv[src]*dinv[dst], self-loop handled analytically.

#define DI 256
#define DH 128
#define DO 64

__global__ void deg_count(const int* __restrict__ dst, float* __restrict__ deg, int E) {
    int e = blockIdx.x * blockDim.x + threadIdx.x;
    if (e < E) atomicAdd(&deg[dst[e]], 1.0f);
}

__global__ void make_dinv(float* __restrict__ deg, int n) {
    int i = blockIdx.x * blockDim.x + threadIdx.x;
    if (i < n) deg[i] = rsqrtf(deg[i] + 1.0f);   // +1 self loop; always > 0
}

// Y[n,M] = X[n,K] @ W[K,M], row-major. Block = 256 threads = (256/M) rows.
template<int K, int M>
__global__ void rowgemm(const float* __restrict__ X, const float* __restrict__ W,
                        float* __restrict__ Y, int n) {
    constexpr int ROWS = 256 / M;
    __shared__ float xs[ROWS][K];
    int r0 = blockIdx.x * ROWS;
    for (int idx = threadIdx.x; idx < ROWS * K; idx += 256) {
        int rr = idx / K, kk = idx % K;
        int row = r0 + rr;
        xs[rr][kk] = (row < n) ? X[(long)row * K + kk] : 0.f;
    }
    __syncthreads();
    int rr = threadIdx.x / M;
    int j  = threadIdx.x % M;
    int row = r0 + rr;
    if (row >= n) return;
    float acc = 0.f;
#pragma unroll 8
    for (int k = 0; k < K; ++k) acc += xs[rr][k] * W[k * M + j];
    Y[(long)row * M + j] = acc;
}

// agg[dst] += H[src] * dinv[src]*dinv[dst], one edge per 256/M-thread group.
template<int M>
__global__ void scatter_edges(const int* __restrict__ src, const int* __restrict__ dst,
                              const float* __restrict__ dinv, const float* __restrict__ H,
                              float* __restrict__ agg, int E) {
    constexpr int EPB = 256 / M;
    int e = blockIdx.x * EPB + threadIdx.x / M;
    int j = threadIdx.x % M;
    if (e >= E) return;
    int s = src[e], d = dst[e];
    float nm = dinv[s] * dinv[d];
    atomicAdd(&agg[(long)d * M + j], H[(long)s * M + j] * nm);
}

// h = relu(agg + dinv^2 * h0 + b1), written in place into agg.
__global__ void finish1(const float* __restrict__ h0, const float* __restrict__ dinv,
                        const float* __restrict__ b1, float* __restrict__ agg, int total) {
    int idx = blockIdx.x * blockDim.x + threadIdx.x;
    if (idx >= total) return;
    int i = idx / DH, j = idx % DH;
    float di = dinv[i];
    float v = agg[idx] + di * di * h0[idx] + b1[j];
    agg[idx] = fmaxf(v, 0.f);
}

// out = agg + dinv^2 * h1 + b2
__global__ void finish2(const float* __restrict__ h1, const float* __restrict__ dinv,
                        const float* __restrict__ b2, const float* __restrict__ agg,
                        float* __restrict__ out, int total) {
    int idx = blockIdx.x * blockDim.x + threadIdx.x;
    if (idx >= total) return;
    int i = idx / DO, j = idx % DO;
    float di = dinv[i];
    out[idx] = agg[idx] + di * di * h1[idx] + b2[j];
}

extern "C" void kernel_launch(void* const* d_in, const int* in_sizes, int n_in,
                              void* d_out, int out_size, void* d_ws, size_t ws_size,
                              hipStream_t stream) {
    const float* x   = (const float*)d_in[0];
    const int*   ei  = (const int*)d_in[1];     // [2, E] int32
    const float* W1  = (const float*)d_in[2];
    const float* b1  = (const float*)d_in[3];
    const float* W2  = (const float*)d_in[4];
    const float* b2  = (const float*)d_in[5];
    float* out = (float*)d_out;

    const int n = in_sizes[0] / DI;             // 50000
    const int E = in_sizes[1] / 2;              // 800000
    const int* src = ei;
    const int* dst = ei + E;

    // workspace layout (floats): dinv[n] | h0[n*DH] | agg1[n*DH]
    // h1 (n*DO) and agg2 (n*DO) reuse the h0 buffer once h0 is dead.
    float* ws   = (float*)d_ws;
    float* dinv = ws;
    float* h0   = ws + n;
    float* agg1 = h0 + (long)n * DH;
    float* h1   = h0;                  // first n*DO floats of h0 region
    float* agg2 = h0 + (long)n * DO;   // second n*DO floats of h0 region

    // deg -> dinv
    hipMemsetAsync(dinv, 0, (size_t)n * 4, stream);
    deg_count<<<(E + 255) / 256, 256, 0, stream>>>(dst, dinv, E);
    make_dinv<<<(n + 255) / 256, 256, 0, stream>>>(dinv, n);

    // layer 1
    rowgemm<DI, DH><<<(n + 1) / 2, 256, 0, stream>>>(x, W1, h0, n);
    hipMemsetAsync(agg1, 0, (size_t)n * DH * 4, stream);
    scatter_edges<DH><<<(E + 1) / 2, 256, 0, stream>>>(src, dst, dinv, h0, agg1, E);
    finish1<<<(n * DH + 255) / 256, 256, 0, stream>>>(h0, dinv, b1, agg1, n * DH);

    // layer 2 (agg1 now holds h)
    rowgemm<DH, DO><<<(n + 3) / 4, 256, 0, stream>>>(agg1, W2, h1, n);
    hipMemsetAsync(agg2, 0, (size_t)n * DO * 4, stream);
    scatter_edges<DO><<<(E + 3) / 4, 256, 0, stream>>>(src, dst, dinv, h1, agg2, E);
    finish2<<<(n * DO + 255) / 256, 256, 0, stream>>>(h1, dinv, b2, agg2, out, n * DO);
}

// Round 2
// 506.608 us; speedup vs baseline: 1.8299x; 1.8299x over previous
//
#include <hip/hip_runtime.h>

// GCN 2-layer, CSR-gather formulation (no fp32 atomics):
//   deg = indeg+1; dinv = rsqrt(deg)
//   Hs = dinv[i] * (X @ W)          (GEMM epilogue scale)
//   Y[i] = act( dinv[i] * (sum_{s in N(i)} Hs[s] + Hs[i]) + b )
// CSR built on-device every call (harness re-poisons ws).

#define DI 256
#define DH 128
#define DO 64

__global__ void deg_count(const int* __restrict__ dst, int* __restrict__ deg, int E) {
    int e = blockIdx.x * blockDim.x + threadIdx.x;
    if (e < E) atomicAdd(&deg[dst[e]], 1);
}

// per-256-block exclusive scan, block sums out
__global__ void scan1(const int* __restrict__ deg, int* __restrict__ off,
                      int* __restrict__ bsum, int n) {
    __shared__ int sh[256];
    int i = blockIdx.x * 256 + threadIdx.x;
    int v = (i < n) ? deg[i] : 0;
    sh[threadIdx.x] = v;
    __syncthreads();
    for (int o = 1; o < 256; o <<= 1) {
        int t = (threadIdx.x >= o) ? sh[threadIdx.x - o] : 0;
        __syncthreads();
        sh[threadIdx.x] += t;
        __syncthreads();
    }
    if (i < n) off[i] = sh[threadIdx.x] - v;       // exclusive
    if (threadIdx.x == 255) bsum[blockIdx.x] = sh[255];
}

// single-block exclusive scan of block sums (nb <= 256)
__global__ void scan2(int* __restrict__ bsum, int nb) {
    __shared__ int sh[256];
    int v = (threadIdx.x < nb) ? bsum[threadIdx.x] : 0;
    sh[threadIdx.x] = v;
    __syncthreads();
    for (int o = 1; o < 256; o <<= 1) {
        int t = (threadIdx.x >= o) ? sh[threadIdx.x - o] : 0;
        __syncthreads();
        sh[threadIdx.x] += t;
        __syncthreads();
    }
    bsum[threadIdx.x] = sh[threadIdx.x] - v;
}

__global__ void scan3(int* __restrict__ off, const int* __restrict__ bsum,
                      int* __restrict__ cursor, int n, int E) {
    int i = blockIdx.x * 256 + threadIdx.x;
    if (i < n) {
        int o = off[i] + bsum[blockIdx.x];
        off[i] = o;
        cursor[i] = o;
    }
    if (i == 0) off[n] = E;
}

// in-place: dinv aliases deg (deg dead after scan1)
__global__ void make_dinv(const int* __restrict__ deg, float* __restrict__ dinv, int n) {
    int i = blockIdx.x * blockDim.x + threadIdx.x;
    if (i < n) dinv[i] = rsqrtf((float)deg[i] + 1.0f);
}

__global__ void fill_csr(const int* __restrict__ src, const int* __restrict__ dst,
                         int* __restrict__ cursor, int* __restrict__ csr, int E) {
    int e = blockIdx.x * blockDim.x + threadIdx.x;
    if (e < E) {
        int p = atomicAdd(&cursor[dst[e]], 1);
        csr[p] = src[e];
    }
}

// Y[n,M] = dinv[i] * (X[n,K] @ W[K,M]); 256 threads = 256/M rows per block
template<int K, int M>
__global__ void rowgemm_s(const float* __restrict__ X, const float* __restrict__ W,
                          const float* __restrict__ dinv, float* __restrict__ Y, int n) {
    constexpr int ROWS = 256 / M;
    __shared__ float xs[ROWS][K];
    int r0 = blockIdx.x * ROWS;
    for (int idx = threadIdx.x; idx < ROWS * K; idx += 256) {
        int rr = idx / K, kk = idx % K;
        int row = r0 + rr;
        xs[rr][kk] = (row < n) ? X[(long)row * K + kk] : 0.f;
    }
    __syncthreads();
    int rr = threadIdx.x / M;
    int j  = threadIdx.x % M;
    int row = r0 + rr;
    if (row >= n) return;
    float acc = 0.f;
#pragma unroll 8
    for (int k = 0; k < K; ++k) acc += xs[rr][k] * W[k * M + j];
    Y[(long)row * M + j] = dinv[row] * acc;
}

// Y[i] = act(dinv[i]*(sum Hs[src] + Hs[i]) + b); M/4 threads per node, float4
template<int M, bool RELU>
__global__ void gather_fin(const int* __restrict__ off, const int* __restrict__ csr,
                           const float* __restrict__ Hs, const float* __restrict__ dinv,
                           const float* __restrict__ b, float* __restrict__ Y, int n) {
    constexpr int G = M / 4;          // threads per node
    constexpr int NPB = 256 / G;      // nodes per block
    int g = threadIdx.x / G;
    int j = threadIdx.x % G;
    int i = blockIdx.x * NPB + g;
    if (i >= n) return;
    const float4* H4 = (const float4*)Hs;
    float4 acc = H4[(long)i * G + j];                 // self loop
    int k = off[i], ke = off[i + 1];
    for (; k + 3 < ke; k += 4) {
        int s0 = csr[k], s1 = csr[k + 1], s2 = csr[k + 2], s3 = csr[k + 3];
        float4 a0 = H4[(long)s0 * G + j];
        float4 a1 = H4[(long)s1 * G + j];
        float4 a2 = H4[(long)s2 * G + j];
        float4 a3 = H4[(long)s3 * G + j];
        acc.x += a0.x + a1.x + a2.x + a3.x;
        acc.y += a0.y + a1.y + a2.y + a3.y;
        acc.z += a0.z + a1.z + a2.z + a3.z;
        acc.w += a0.w + a1.w + a2.w + a3.w;
    }
    for (; k < ke; ++k) {
        float4 a = H4[(long)csr[k] * G + j];
        acc.x += a.x; acc.y += a.y; acc.z += a.z; acc.w += a.w;
    }
    float di = dinv[i];
    float4 bb = ((const float4*)b)[j];
    float4 r;
    r.x = di * acc.x + bb.x;
    r.y = di * acc.y + bb.y;
    r.z = di * acc.z + bb.z;
    r.w = di * acc.w + bb.w;
    if (RELU) {
        r.x = fmaxf(r.x, 0.f); r.y = fmaxf(r.y, 0.f);
        r.z = fmaxf(r.z, 0.f); r.w = fmaxf(r.w, 0.f);
    }
    ((float4*)Y)[(long)i * G + j] = r;
}

extern "C" void kernel_launch(void* const* d_in, const int* in_sizes, int n_in,
                              void* d_out, int out_size, void* d_ws, size_t ws_size,
                              hipStream_t stream) {
    const float* x  = (const float*)d_in[0];
    const int*   ei = (const int*)d_in[1];
    const float* W1 = (const float*)d_in[2];
    const float* b1 = (const float*)d_in[3];
    const float* W2 = (const float*)d_in[4];
    const float* b2 = (const float*)d_in[5];
    float* out = (float*)d_out;

    const int n = in_sizes[0] / DI;   // 50000
    const int E = in_sizes[1] / 2;    // 800000
    const int* src = ei;
    const int* dst = ei + E;
    const int nb = (n + 255) / 256;
    const int np = nb * 256;          // padded n

    // ws layout (4B elements):
    // deg/dinv[np] | off[np+256] | cursor[np] | bsum[256] | csr[E] | h0s[n*DH] | h[n*DH]
    int*   deg    = (int*)d_ws;
    float* dinv   = (float*)d_ws;
    int*   off    = deg + np;
    int*   cursor = off + np + 256;
    int*   bsum   = cursor + np;
    int*   csr    = bsum + 256;
    float* h0s    = (float*)(csr + E);
    float* h      = h0s + (long)n * DH;
    float* h1s    = h0s;              // reuse after gather1

    const int eb = (E + 255) / 256;

    hipMemsetAsync(deg, 0, (size_t)n * 4, stream);
    deg_count<<<eb, 256, 0, stream>>>(dst, deg, E);
    scan1<<<nb, 256, 0, stream>>>(deg, off, bsum, n);
    scan2<<<1, 256, 0, stream>>>(bsum, nb);
    scan3<<<nb, 256, 0, stream>>>(off, bsum, cursor, n, E);
    make_dinv<<<nb, 256, 0, stream>>>(deg, dinv, n);
    fill_csr<<<eb, 256, 0, stream>>>(src, dst, cursor, csr, E);

    // layer 1: h0s = dinv*(x@W1); h = relu(dinv*(gather+self) + b1)
    rowgemm_s<DI, DH><<<(n + 1) / 2, 256, 0, stream>>>(x, W1, dinv, h0s, n);
    gather_fin<DH, true><<<(n + 7) / 8, 256, 0, stream>>>(off, csr, h0s, dinv, b1, h, n);

    // layer 2: h1s = dinv*(h@W2); out = dinv*(gather+self) + b2
    rowgemm_s<DH, DO><<<(n + 3) / 4, 256, 0, stream>>>(h, W2, dinv, h1s, n);
    gather_fin<DO, false><<<(n + 15) / 16, 256, 0, stream>>>(off, csr, h1s, dinv, b2, out, n);
}

// Round 3
// 350.736 us; speedup vs baseline: 2.6431x; 1.4444x over previous
//
#include <hip/hip_runtime.h>

// GCN 2-layer, CSR-gather formulation (no fp32 atomics):
//   deg = indeg+1; dinv = rsqrt(deg)
//   Hs = dinv[i] * (X @ W)          (GEMM epilogue scale)
//   Y[i] = act( dinv[i] * (sum_{s in N(i)} Hs[s] + Hs[i]) + b )
// R3: register-tiled fp32 GEMM (128xM tile, KT=32, 8x8 per thread).

#define DI 256
#define DH 128
#define DO 64

__global__ void deg_count(const int* __restrict__ dst, int* __restrict__ deg, int E) {
    int e = blockIdx.x * blockDim.x + threadIdx.x;
    if (e < E) atomicAdd(&deg[dst[e]], 1);
}

__global__ void scan1(const int* __restrict__ deg, int* __restrict__ off,
                      int* __restrict__ bsum, int n) {
    __shared__ int sh[256];
    int i = blockIdx.x * 256 + threadIdx.x;
    int v = (i < n) ? deg[i] : 0;
    sh[threadIdx.x] = v;
    __syncthreads();
    for (int o = 1; o < 256; o <<= 1) {
        int t = (threadIdx.x >= o) ? sh[threadIdx.x - o] : 0;
        __syncthreads();
        sh[threadIdx.x] += t;
        __syncthreads();
    }
    if (i < n) off[i] = sh[threadIdx.x] - v;
    if (threadIdx.x == 255) bsum[blockIdx.x] = sh[255];
}

__global__ void scan2(int* __restrict__ bsum, int nb) {
    __shared__ int sh[256];
    int v = (threadIdx.x < nb) ? bsum[threadIdx.x] : 0;
    sh[threadIdx.x] = v;
    __syncthreads();
    for (int o = 1; o < 256; o <<= 1) {
        int t = (threadIdx.x >= o) ? sh[threadIdx.x - o] : 0;
        __syncthreads();
        sh[threadIdx.x] += t;
        __syncthreads();
    }
    bsum[threadIdx.x] = sh[threadIdx.x] - v;
}

__global__ void scan3(int* __restrict__ off, const int* __restrict__ bsum,
                      int* __restrict__ cursor, int n, int E) {
    int i = blockIdx.x * 256 + threadIdx.x;
    if (i < n) {
        int o = off[i] + bsum[blockIdx.x];
        off[i] = o;
        cursor[i] = o;
    }
    if (i == 0) off[n] = E;
}

__global__ void make_dinv(const int* __restrict__ deg, float* __restrict__ dinv, int n) {
    int i = blockIdx.x * blockDim.x + threadIdx.x;
    if (i < n) dinv[i] = rsqrtf((float)deg[i] + 1.0f);
}

__global__ void fill_csr(const int* __restrict__ src, const int* __restrict__ dst,
                         int* __restrict__ cursor, int* __restrict__ csr, int E) {
    int e = blockIdx.x * blockDim.x + threadIdx.x;
    if (e < E) {
        int p = atomicAdd(&cursor[dst[e]], 1);
        csr[p] = src[e];
    }
}

// Y[n,M] = dinv[row] * (X[n,K] @ W[K,M]).
// BM=128 rows/block, KT=32, 256 threads. TX=M/8 col-groups; each thread owns
// cols {tx*4..+3, M/2+tx*4..+3} (2-way-bank-free Ws reads) and RPT=128/TY rows.
template<int K, int M>
__global__ __launch_bounds__(256) void tile_gemm(const float* __restrict__ X,
                                                 const float* __restrict__ W,
                                                 const float* __restrict__ dinv,
                                                 float* __restrict__ Y, int n) {
    constexpr int BM = 128, KT = 32;
    constexpr int TX = M / 8;          // 16 (L1) or 8 (L2)
    constexpr int TY = 256 / TX;       // 16 or 32
    constexpr int RPT = BM / TY;       // 8 or 4
    constexpr int XS = BM + 4;         // pad: soften transpose-write conflicts
    __shared__ float Xs[KT][XS];
    __shared__ float Ws[KT][M];
    const int tx = threadIdx.x % TX;
    const int ty = threadIdx.x / TX;
    const int r0 = blockIdx.x * BM;
    float acc[RPT][8] = {};

    for (int k0 = 0; k0 < K; k0 += KT) {
        // X tile (transposed into LDS): 128x32 floats, 4 float4/thread
#pragma unroll
        for (int i = 0; i < BM * KT / 1024; ++i) {
            int idx = threadIdx.x + i * 256;
            int row = idx >> 3;            // / (KT/4)
            int kc  = idx & 7;
            float4 v = make_float4(0.f, 0.f, 0.f, 0.f);
            int gr = r0 + row;
            if (gr < n) v = *(const float4*)&X[(long)gr * K + k0 + kc * 4];
            Xs[kc * 4 + 0][row] = v.x;
            Xs[kc * 4 + 1][row] = v.y;
            Xs[kc * 4 + 2][row] = v.z;
            Xs[kc * 4 + 3][row] = v.w;
        }
        // W tile: KT x M floats
#pragma unroll
        for (int i = 0; i < KT * M / 1024; ++i) {
            int idx = threadIdx.x + i * 256;
            int kk = idx / (M / 4);
            int jc = idx % (M / 4);
            *(float4*)&Ws[kk][jc * 4] = *(const float4*)&W[(long)(k0 + kk) * M + jc * 4];
        }
        __syncthreads();
#pragma unroll 4
        for (int k = 0; k < KT; ++k) {
            float xv[RPT];
#pragma unroll
            for (int r = 0; r < RPT; r += 4)
                *(float4*)&xv[r] = *(const float4*)&Xs[k][ty * RPT + r];
            float wv[8];
            *(float4*)&wv[0] = *(const float4*)&Ws[k][tx * 4];
            *(float4*)&wv[4] = *(const float4*)&Ws[k][M / 2 + tx * 4];
#pragma unroll
            for (int r = 0; r < RPT; ++r)
#pragma unroll
                for (int j = 0; j < 8; ++j)
                    acc[r][j] += xv[r] * wv[j];
        }
        __syncthreads();
    }
#pragma unroll
    for (int r = 0; r < RPT; ++r) {
        int row = r0 + ty * RPT + r;
        if (row < n) {
            float di = dinv[row];
            float4 o0 = {di * acc[r][0], di * acc[r][1], di * acc[r][2], di * acc[r][3]};
            float4 o1 = {di * acc[r][4], di * acc[r][5], di * acc[r][6], di * acc[r][7]};
            *(float4*)&Y[(long)row * M + tx * 4] = o0;
            *(float4*)&Y[(long)row * M + M / 2 + tx * 4] = o1;
        }
    }
}

// Y[i] = act(dinv[i]*(sum Hs[src] + Hs[i]) + b); M/4 threads per node, float4
template<int M, bool RELU>
__global__ void gather_fin(const int* __restrict__ off, const int* __restrict__ csr,
                           const float* __restrict__ Hs, const float* __restrict__ dinv,
                           const float* __restrict__ b, float* __restrict__ Y, int n) {
    constexpr int G = M / 4;
    constexpr int NPB = 256 / G;
    int g = threadIdx.x / G;
    int j = threadIdx.x % G;
    int i = blockIdx.x * NPB + g;
    if (i >= n) return;
    const float4* H4 = (const float4*)Hs;
    float4 acc = H4[(long)i * G + j];
    int k = off[i], ke = off[i + 1];
    for (; k + 3 < ke; k += 4) {
        int s0 = csr[k], s1 = csr[k + 1], s2 = csr[k + 2], s3 = csr[k + 3];
        float4 a0 = H4[(long)s0 * G + j];
        float4 a1 = H4[(long)s1 * G + j];
        float4 a2 = H4[(long)s2 * G + j];
        float4 a3 = H4[(long)s3 * G + j];
        acc.x += a0.x + a1.x + a2.x + a3.x;
        acc.y += a0.y + a1.y + a2.y + a3.y;
        acc.z += a0.z + a1.z + a2.z + a3.z;
        acc.w += a0.w + a1.w + a2.w + a3.w;
    }
    for (; k < ke; ++k) {
        float4 a = H4[(long)csr[k] * G + j];
        acc.x += a.x; acc.y += a.y; acc.z += a.z; acc.w += a.w;
    }
    float di = dinv[i];
    float4 bb = ((const float4*)b)[j];
    float4 r;
    r.x = di * acc.x + bb.x;
    r.y = di * acc.y + bb.y;
    r.z = di * acc.z + bb.z;
    r.w = di * acc.w + bb.w;
    if (RELU) {
        r.x = fmaxf(r.x, 0.f); r.y = fmaxf(r.y, 0.f);
        r.z = fmaxf(r.z, 0.f); r.w = fmaxf(r.w, 0.f);
    }
    ((float4*)Y)[(long)i * G + j] = r;
}

extern "C" void kernel_launch(void* const* d_in, const int* in_sizes, int n_in,
                              void* d_out, int out_size, void* d_ws, size_t ws_size,
                              hipStream_t stream) {
    const float* x  = (const float*)d_in[0];
    const int*   ei = (const int*)d_in[1];
    const float* W1 = (const float*)d_in[2];
    const float* b1 = (const float*)d_in[3];
    const float* W2 = (const float*)d_in[4];
    const float* b2 = (const float*)d_in[5];
    float* out = (float*)d_out;

    const int n = in_sizes[0] / DI;   // 50000
    const int E = in_sizes[1] / 2;    // 800000
    const int* src = ei;
    const int* dst = ei + E;
    const int nb = (n + 255) / 256;
    const int np = nb * 256;

    // ws: deg/dinv[np] | off[np+256] | cursor[np] | bsum[256] | csr[E] | h0s[n*DH] | h[n*DH]
    int*   deg    = (int*)d_ws;
    float* dinv   = (float*)d_ws;
    int*   off    = deg + np;
    int*   cursor = off + np + 256;
    int*   bsum   = cursor + np;
    int*   csr    = bsum + 256;
    float* h0s    = (float*)(csr + E);
    float* h      = h0s + (long)n * DH;
    float* h1s    = h0s;

    const int eb = (E + 255) / 256;

    hipMemsetAsync(deg, 0, (size_t)n * 4, stream);
    deg_count<<<eb, 256, 0, stream>>>(dst, deg, E);
    scan1<<<nb, 256, 0, stream>>>(deg, off, bsum, n);
    scan2<<<1, 256, 0, stream>>>(bsum, nb);
    scan3<<<nb, 256, 0, stream>>>(off, bsum, cursor, n, E);
    make_dinv<<<nb, 256, 0, stream>>>(deg, dinv, n);
    fill_csr<<<eb, 256, 0, stream>>>(src, dst, cursor, csr, E);

    const int gblk = (n + 127) / 128;
    // layer 1
    tile_gemm<DI, DH><<<gblk, 256, 0, stream>>>(x, W1, dinv, h0s, n);
    gather_fin<DH, true><<<(n + 7) / 8, 256, 0, stream>>>(off, csr, h0s, dinv, b1, h, n);
    // layer 2
    tile_gemm<DH, DO><<<gblk, 256, 0, stream>>>(h, W2, dinv, h1s, n);
    gather_fin<DO, false><<<(n + 15) / 16, 256, 0, stream>>>(off, csr, h1s, dinv, b2, out, n);
}

// Round 4
// 332.771 us; speedup vs baseline: 2.7858x; 1.0540x over previous
//
#include <hip/hip_runtime.h>

// GCN 2-layer, CSR-gather formulation (no fp32 atomics):
//   deg = indeg+1; dinv = rsqrt(deg)
//   Hs = dinv[i] * (X @ W)          (GEMM epilogue scale)
//   Y[i] = act( dinv[i] * (sum_{s in N(i)} Hs[s] + Hs[i]) + b )
// R4: BM=64 tiles -> 782 blocks (was 391), ~25KB LDS -> 6 blocks/CU.

#define DI 256
#define DH 128
#define DO 64

__global__ void deg_count(const int* __restrict__ dst, int* __restrict__ deg, int E) {
    int e = blockIdx.x * blockDim.x + threadIdx.x;
    if (e < E) atomicAdd(&deg[dst[e]], 1);
}

__global__ void scan1(const int* __restrict__ deg, int* __restrict__ off,
                      int* __restrict__ bsum, int n) {
    __shared__ int sh[256];
    int i = blockIdx.x * 256 + threadIdx.x;
    int v = (i < n) ? deg[i] : 0;
    sh[threadIdx.x] = v;
    __syncthreads();
    for (int o = 1; o < 256; o <<= 1) {
        int t = (threadIdx.x >= o) ? sh[threadIdx.x - o] : 0;
        __syncthreads();
        sh[threadIdx.x] += t;
        __syncthreads();
    }
    if (i < n) off[i] = sh[threadIdx.x] - v;
    if (threadIdx.x == 255) bsum[blockIdx.x] = sh[255];
}

__global__ void scan2(int* __restrict__ bsum, int nb) {
    __shared__ int sh[256];
    int v = (threadIdx.x < nb) ? bsum[threadIdx.x] : 0;
    sh[threadIdx.x] = v;
    __syncthreads();
    for (int o = 1; o < 256; o <<= 1) {
        int t = (threadIdx.x >= o) ? sh[threadIdx.x - o] : 0;
        __syncthreads();
        sh[threadIdx.x] += t;
        __syncthreads();
    }
    bsum[threadIdx.x] = sh[threadIdx.x] - v;
}

__global__ void scan3(int* __restrict__ off, const int* __restrict__ bsum,
                      int* __restrict__ cursor, int n, int E) {
    int i = blockIdx.x * 256 + threadIdx.x;
    if (i < n) {
        int o = off[i] + bsum[blockIdx.x];
        off[i] = o;
        cursor[i] = o;
    }
    if (i == 0) off[n] = E;
}

__global__ void make_dinv(const int* __restrict__ deg, float* __restrict__ dinv, int n) {
    int i = blockIdx.x * blockDim.x + threadIdx.x;
    if (i < n) dinv[i] = rsqrtf((float)deg[i] + 1.0f);
}

__global__ void fill_csr(const int* __restrict__ src, const int* __restrict__ dst,
                         int* __restrict__ cursor, int* __restrict__ csr, int E) {
    int e = blockIdx.x * blockDim.x + threadIdx.x;
    if (e < E) {
        int p = atomicAdd(&cursor[dst[e]], 1);
        csr[p] = src[e];
    }
}

// Y[n,M] = dinv[row] * (X[n,K] @ W[K,M]).
// BM=64 rows/block, KT=32, 256 threads. TX=M/8 col-groups, each thread owns
// cols {tx*4..+3, M/2+tx*4..+3} and RPT=64/TY rows.
template<int K, int M>
__global__ __launch_bounds__(256) void tile_gemm(const float* __restrict__ X,
                                                 const float* __restrict__ W,
                                                 const float* __restrict__ dinv,
                                                 float* __restrict__ Y, int n) {
    constexpr int BM = 64, KT = 32;
    constexpr int TX = M / 8;          // 16 (L1) or 8 (L2)
    constexpr int TY = 256 / TX;       // 16 or 32
    constexpr int RPT = BM / TY;       // 4 or 2
    constexpr int XS = BM + 4;         // 68: keeps every Xs[k] row 16B-aligned
    __shared__ float Xs[KT][XS];
    __shared__ float Ws[KT][M];
    const int tx = threadIdx.x % TX;
    const int ty = threadIdx.x / TX;
    const int r0 = blockIdx.x * BM;
    float acc[RPT][8] = {};

    for (int k0 = 0; k0 < K; k0 += KT) {
        // X tile transposed into LDS: 64x32 floats = 512 float4, 2 per thread
#pragma unroll
        for (int i = 0; i < BM * KT / 1024; ++i) {
            int idx = threadIdx.x + i * 256;
            int row = idx >> 3;            // idx / (KT/4)
            int kc  = idx & 7;
            float4 v = make_float4(0.f, 0.f, 0.f, 0.f);
            int gr = r0 + row;
            if (gr < n) v = *(const float4*)&X[(long)gr * K + k0 + kc * 4];
            Xs[kc * 4 + 0][row] = v.x;
            Xs[kc * 4 + 1][row] = v.y;
            Xs[kc * 4 + 2][row] = v.z;
            Xs[kc * 4 + 3][row] = v.w;
        }
        // W tile: KT x M floats
#pragma unroll
        for (int i = 0; i < KT * M / 1024; ++i) {
            int idx = threadIdx.x + i * 256;
            int kk = idx / (M / 4);
            int jc = idx % (M / 4);
            *(float4*)&Ws[kk][jc * 4] = *(const float4*)&W[(long)(k0 + kk) * M + jc * 4];
        }
        __syncthreads();
#pragma unroll 8
        for (int k = 0; k < KT; ++k) {
            float xv[RPT];
#pragma unroll
            for (int r = 0; r < RPT; ++r) xv[r] = Xs[k][ty * RPT + r];
            float wv[8];
            *(float4*)&wv[0] = *(const float4*)&Ws[k][tx * 4];
            *(float4*)&wv[4] = *(const float4*)&Ws[k][M / 2 + tx * 4];
#pragma unroll
            for (int r = 0; r < RPT; ++r)
#pragma unroll
                for (int j = 0; j < 8; ++j)
                    acc[r][j] += xv[r] * wv[j];
        }
        __syncthreads();
    }
#pragma unroll
    for (int r = 0; r < RPT; ++r) {
        int row = r0 + ty * RPT + r;
        if (row < n) {
            float di = dinv[row];
            float4 o0 = {di * acc[r][0], di * acc[r][1], di * acc[r][2], di * acc[r][3]};
            float4 o1 = {di * acc[r][4], di * acc[r][5], di * acc[r][6], di * acc[r][7]};
            *(float4*)&Y[(long)row * M + tx * 4] = o0;
            *(float4*)&Y[(long)row * M + M / 2 + tx * 4] = o1;
        }
    }
}

// Y[i] = act(dinv[i]*(sum Hs[src] + Hs[i]) + b); M/4 threads per node, float4
template<int M, bool RELU>
__global__ void gather_fin(const int* __restrict__ off, const int* __restrict__ csr,
                           const float* __restrict__ Hs, const float* __restrict__ dinv,
                           const float* __restrict__ b, float* __restrict__ Y, int n) {
    constexpr int G = M / 4;
    constexpr int NPB = 256 / G;
    int g = threadIdx.x / G;
    int j = threadIdx.x % G;
    int i = blockIdx.x * NPB + g;
    if (i >= n) return;
    const float4* H4 = (const float4*)Hs;
    float4 acc = H4[(long)i * G + j];
    int k = off[i], ke = off[i + 1];
    for (; k + 3 < ke; k += 4) {
        int s0 = csr[k], s1 = csr[k + 1], s2 = csr[k + 2], s3 = csr[k + 3];
        float4 a0 = H4[(long)s0 * G + j];
        float4 a1 = H4[(long)s1 * G + j];
        float4 a2 = H4[(long)s2 * G + j];
        float4 a3 = H4[(long)s3 * G + j];
        acc.x += a0.x + a1.x + a2.x + a3.x;
        acc.y += a0.y + a1.y + a2.y + a3.y;
        acc.z += a0.z + a1.z + a2.z + a3.z;
        acc.w += a0.w + a1.w + a2.w + a3.w;
    }
    for (; k < ke; ++k) {
        float4 a = H4[(long)csr[k] * G + j];
        acc.x += a.x; acc.y += a.y; acc.z += a.z; acc.w += a.w;
    }
    float di = dinv[i];
    float4 bb = ((const float4*)b)[j];
    float4 r;
    r.x = di * acc.x + bb.x;
    r.y = di * acc.y + bb.y;
    r.z = di * acc.z + bb.z;
    r.w = di * acc.w + bb.w;
    if (RELU) {
        r.x = fmaxf(r.x, 0.f); r.y = fmaxf(r.y, 0.f);
        r.z = fmaxf(r.z, 0.f); r.w = fmaxf(r.w, 0.f);
    }
    ((float4*)Y)[(long)i * G + j] = r;
}

extern "C" void kernel_launch(void* const* d_in, const int* in_sizes, int n_in,
                              void* d_out, int out_size, void* d_ws, size_t ws_size,
                              hipStream_t stream) {
    const float* x  = (const float*)d_in[0];
    const int*   ei = (const int*)d_in[1];
    const float* W1 = (const float*)d_in[2];
    const float* b1 = (const float*)d_in[3];
    const float* W2 = (const float*)d_in[4];
    const float* b2 = (const float*)d_in[5];
    float* out = (float*)d_out;

    const int n = in_sizes[0] / DI;   // 50000
    const int E = in_sizes[1] / 2;    // 800000
    const int* src = ei;
    const int* dst = ei + E;
    const int nb = (n + 255) / 256;
    const int np = nb * 256;

    // ws: deg/dinv[np] | off[np+256] | cursor[np] | bsum[256] | csr[E] | h0s[n*DH] | h[n*DH]
    int*   deg    = (int*)d_ws;
    float* dinv   = (float*)d_ws;
    int*   off    = deg + np;
    int*   cursor = off + np + 256;
    int*   bsum   = cursor + np;
    int*   csr    = bsum + 256;
    float* h0s    = (float*)(csr + E);
    float* h      = h0s + (long)n * DH;
    float* h1s    = h0s;

    const int eb = (E + 255) / 256;

    hipMemsetAsync(deg, 0, (size_t)n * 4, stream);
    deg_count<<<eb, 256, 0, stream>>>(dst, deg, E);
    scan1<<<nb, 256, 0, stream>>>(deg, off, bsum, n);
    scan2<<<1, 256, 0, stream>>>(bsum, nb);
    scan3<<<nb, 256, 0, stream>>>(off, bsum, cursor, n, E);
    make_dinv<<<nb, 256, 0, stream>>>(deg, dinv, n);
    fill_csr<<<eb, 256, 0, stream>>>(src, dst, cursor, csr, E);

    const int gblk = (n + 63) / 64;
    // layer 1
    tile_gemm<DI, DH><<<gblk, 256, 0, stream>>>(x, W1, dinv, h0s, n);
    gather_fin<DH, true><<<(n + 7) / 8, 256, 0, stream>>>(off, csr, h0s, dinv, b1, h, n);
    // layer 2
    tile_gemm<DH, DO><<<gblk, 256, 0, stream>>>(h, W2, dinv, h1s, n);
    gather_fin<DO, false><<<(n + 15) / 16, 256, 0, stream>>>(off, csr, h1s, dinv, b2, out, n);
}

// Round 5
// 269.056 us; speedup vs baseline: 3.4454x; 1.2368x over previous
//
#include <hip/hip_runtime.h>

// GCN 2-layer, CSR-gather + bf16 MFMA GEMMs.
//   deg = indeg+1; dinv = rsqrt(deg)
//   h0s = bf16( dinv * (X @ W1) )          (MFMA, fp32 X cvt on the fly)
//   h   = bf16( relu(dinv*(gather h0s + self) + b1) )
//   h1s = bf16( dinv * (h @ W2) )          (MFMA)
//   out = fp32( dinv*(gather h1s + self) + b2 )
// W1/W2 pre-transposed+converted to bf16 [M][K] in ws (B-frags contiguous in K).

#define DI 256
#define DH 128
#define DO 64

typedef unsigned short ushort;
typedef unsigned int uint;
using bf16x8 = __attribute__((ext_vector_type(8))) short;
using f32x4  = __attribute__((ext_vector_type(4))) float;

__device__ __forceinline__ ushort f2b(float f) {
    union { float f; uint u; } v; v.f = f;
    uint r = (v.u + 0x7fffu + ((v.u >> 16) & 1u)) >> 16;   // RNE
    return (ushort)r;
}
__device__ __forceinline__ float blo(uint v) { return __uint_as_float(v << 16); }
__device__ __forceinline__ float bhi(uint v) { return __uint_as_float(v & 0xffff0000u); }

// ---------------- CSR build ----------------
__global__ void deg_count(const int* __restrict__ dst, int* __restrict__ deg, int E) {
    int e = blockIdx.x * blockDim.x + threadIdx.x;
    if (e < E) atomicAdd(&deg[dst[e]], 1);
}

__global__ void scan1(const int* __restrict__ deg, int* __restrict__ off,
                      int* __restrict__ bsum, int n) {
    __shared__ int sh[256];
    int i = blockIdx.x * 256 + threadIdx.x;
    int v = (i < n) ? deg[i] : 0;
    sh[threadIdx.x] = v;
    __syncthreads();
    for (int o = 1; o < 256; o <<= 1) {
        int t = (threadIdx.x >= o) ? sh[threadIdx.x - o] : 0;
        __syncthreads();
        sh[threadIdx.x] += t;
        __syncthreads();
    }
    if (i < n) off[i] = sh[threadIdx.x] - v;
    if (threadIdx.x == 255) bsum[blockIdx.x] = sh[255];
}

__global__ void scan2(int* __restrict__ bsum, int nb) {
    __shared__ int sh[256];
    int v = (threadIdx.x < nb) ? bsum[threadIdx.x] : 0;
    sh[threadIdx.x] = v;
    __syncthreads();
    for (int o = 1; o < 256; o <<= 1) {
        int t = (threadIdx.x >= o) ? sh[threadIdx.x - o] : 0;
        __syncthreads();
        sh[threadIdx.x] += t;
        __syncthreads();
    }
    bsum[threadIdx.x] = sh[threadIdx.x] - v;
}

__global__ void scan3(int* __restrict__ off, const int* __restrict__ bsum,
                      int* __restrict__ cursor, int n, int E) {
    int i = blockIdx.x * 256 + threadIdx.x;
    if (i < n) {
        int o = off[i] + bsum[blockIdx.x];
        off[i] = o;
        cursor[i] = o;
    }
    if (i == 0) off[n] = E;
}

__global__ void make_dinv(const int* __restrict__ deg, float* __restrict__ dinv, int n) {
    int i = blockIdx.x * blockDim.x + threadIdx.x;
    if (i < n) dinv[i] = rsqrtf((float)deg[i] + 1.0f);
}

__global__ void fill_csr(const int* __restrict__ src, const int* __restrict__ dst,
                         int* __restrict__ cursor, int* __restrict__ csr, int E) {
    int e = blockIdx.x * blockDim.x + threadIdx.x;
    if (e < E) {
        int p = atomicAdd(&cursor[dst[e]], 1);
        csr[p] = src[e];
    }
}

// Wt[m][k] = bf16(W[k][m])
__global__ void wt_cvt(const float* __restrict__ W, ushort* __restrict__ Wt, int K, int M) {
    int idx = blockIdx.x * 256 + threadIdx.x;
    if (idx < K * M) {
        int m = idx / K, k = idx % K;
        Wt[idx] = f2b(W[(long)k * M + m]);
    }
}

// ---------------- MFMA GEMM ----------------
// Y[n,M](bf16) = dinv[row] * (X[n,K] @ W[K,M]); Wt is bf16 [M][K].
// BM=64 rows/block, 4 waves; wave w owns all 64 rows x cols [w*M/4, (w+1)*M/4).
// A staged in LDS (XOR-swizzled 16B slots), B-frags read from global (L2-hot).
template<int K, int M, bool INF32>
__global__ __launch_bounds__(256) void mfma_gemm(const void* __restrict__ Xv,
                                                 const ushort* __restrict__ Wt,
                                                 const float* __restrict__ dinv,
                                                 ushort* __restrict__ Y, int n) {
    constexpr int ROWB = K * 2;          // LDS bytes per row
    constexpr int CT = M / 64;           // col-tiles per wave (2 or 1)
    __shared__ ushort Xs[64 * K];
    const int t = threadIdx.x;
    const int r0 = blockIdx.x * 64;

    // ---- stage X tile (64 x K) into LDS as bf16, swizzled ----
    {
        const int row = t & 63, c = t >> 6;          // 4 chunks per row
        const int gr = r0 + row;
        if (INF32) {
            const float4* Xr = (const float4*)((const float*)Xv + (long)gr * K);
#pragma unroll
            for (int j = 0; j < K / 32; ++j) {       // 16B bf16 per j
                float4 a, b;
                if (gr < n) {
                    a = Xr[c * (K / 16) + 2 * j];
                    b = Xr[c * (K / 16) + 2 * j + 1];
                } else {
                    a = make_float4(0.f, 0.f, 0.f, 0.f); b = a;
                }
                ushort u[8] = {f2b(a.x), f2b(a.y), f2b(a.z), f2b(a.w),
                               f2b(b.x), f2b(b.y), f2b(b.z), f2b(b.w)};
                int byte = row * ROWB + c * (K / 2) + j * 16;
                byte ^= (row & 7) << 4;
                *(uint4*)((char*)Xs + byte) = *(const uint4*)u;
            }
        } else {
            const uint4* Xr = (const uint4*)((const ushort*)Xv + (long)gr * K);
#pragma unroll
            for (int j = 0; j < K / 32; ++j) {
                uint4 v = make_uint4(0u, 0u, 0u, 0u);
                if (gr < n) v = Xr[c * (K / 32) + j];
                int byte = row * ROWB + c * (K / 2) + j * 16;
                byte ^= (row & 7) << 4;
                *(uint4*)((char*)Xs + byte) = v;
            }
        }
    }
    __syncthreads();

    // ---- compute ----
    const int w  = t >> 6;
    const int l  = t & 63;
    const int lr = l & 15;       // row-in-tile / col-in-tile
    const int lg = l >> 4;       // k-group
    f32x4 acc[4][CT] = {};

#pragma unroll
    for (int ks = 0; ks < K / 32; ++ks) {
        bf16x8 bfr[CT];
#pragma unroll
        for (int ct = 0; ct < CT; ++ct) {
            int col = w * (M / 4) + ct * 16 + lr;
            bfr[ct] = *(const bf16x8*)&Wt[(long)col * K + ks * 32 + lg * 8];
        }
        bf16x8 afr[4];
#pragma unroll
        for (int rt = 0; rt < 4; ++rt) {
            int row = rt * 16 + lr;
            int byte = row * ROWB + ks * 64 + lg * 16;
            byte ^= (row & 7) << 4;
            afr[rt] = *(const bf16x8*)((const char*)Xs + byte);
        }
#pragma unroll
        for (int rt = 0; rt < 4; ++rt)
#pragma unroll
            for (int ct = 0; ct < CT; ++ct)
                acc[rt][ct] = __builtin_amdgcn_mfma_f32_16x16x32_bf16(
                    afr[rt], bfr[ct], acc[rt][ct], 0, 0, 0);
    }

    // ---- epilogue: scale by dinv, cvt bf16, store ----
#pragma unroll
    for (int rt = 0; rt < 4; ++rt)
#pragma unroll
        for (int i = 0; i < 4; ++i) {
            int gr2 = r0 + rt * 16 + lg * 4 + i;
            if (gr2 < n) {
                float dv = dinv[gr2];
#pragma unroll
                for (int ct = 0; ct < CT; ++ct) {
                    int col = w * (M / 4) + ct * 16 + lr;
                    Y[(long)gr2 * M + col] = f2b(dv * acc[rt][ct][i]);
                }
            }
        }
}

// ---------------- gather + finish ----------------
// Y[i] = act(dinv[i]*(sum Hs[src] + Hs[i]) + b); Hs bf16, M/8 threads/node.
template<int M, bool RELU, bool OUTF32>
__global__ void gather_fin(const int* __restrict__ off, const int* __restrict__ csr,
                           const ushort* __restrict__ Hs, const float* __restrict__ dinv,
                           const float* __restrict__ b, void* __restrict__ Yv, int n) {
    constexpr int G = M / 8;           // threads per node (16B each)
    constexpr int NPB = 256 / G;
    int g = threadIdx.x / G;
    int j = threadIdx.x % G;
    int i = blockIdx.x * NPB + g;
    if (i >= n) return;
    const uint4* H4 = (const uint4*)Hs;
    float acc[8];
    {
        uint4 s = H4[(long)i * G + j];   // self loop
        acc[0] = blo(s.x); acc[1] = bhi(s.x);
        acc[2] = blo(s.y); acc[3] = bhi(s.y);
        acc[4] = blo(s.z); acc[5] = bhi(s.z);
        acc[6] = blo(s.w); acc[7] = bhi(s.w);
    }
    int k = off[i], ke = off[i + 1];
    for (; k + 3 < ke; k += 4) {
        int s0 = csr[k], s1 = csr[k + 1], s2 = csr[k + 2], s3 = csr[k + 3];
        uint4 a0 = H4[(long)s0 * G + j];
        uint4 a1 = H4[(long)s1 * G + j];
        uint4 a2 = H4[(long)s2 * G + j];
        uint4 a3 = H4[(long)s3 * G + j];
        acc[0] += blo(a0.x) + blo(a1.x) + blo(a2.x) + blo(a3.x);
        acc[1] += bhi(a0.x) + bhi(a1.x) + bhi(a2.x) + bhi(a3.x);
        acc[2] += blo(a0.y) + blo(a1.y) + blo(a2.y) + blo(a3.y);
        acc[3] += bhi(a0.y) + bhi(a1.y) + bhi(a2.y) + bhi(a3.y);
        acc[4] += blo(a0.z) + blo(a1.z) + blo(a2.z) + blo(a3.z);
        acc[5] += bhi(a0.z) + bhi(a1.z) + bhi(a2.z) + bhi(a3.z);
        acc[6] += blo(a0.w) + blo(a1.w) + blo(a2.w) + blo(a3.w);
        acc[7] += bhi(a0.w) + bhi(a1.w) + bhi(a2.w) + bhi(a3.w);
    }
    for (; k < ke; ++k) {
        uint4 a = H4[(long)csr[k] * G + j];
        acc[0] += blo(a.x); acc[1] += bhi(a.x);
        acc[2] += blo(a.y); acc[3] += bhi(a.y);
        acc[4] += blo(a.z); acc[5] += bhi(a.z);
        acc[6] += blo(a.w); acc[7] += bhi(a.w);
    }
    float di = dinv[i];
    float4 b0 = ((const float4*)b)[j * 2];
    float4 b1 = ((const float4*)b)[j * 2 + 1];
    float r[8];
    r[0] = di * acc[0] + b0.x; r[1] = di * acc[1] + b0.y;
    r[2] = di * acc[2] + b0.z; r[3] = di * acc[3] + b0.w;
    r[4] = di * acc[4] + b1.x; r[5] = di * acc[5] + b1.y;
    r[6] = di * acc[6] + b1.z; r[7] = di * acc[7] + b1.w;
    if (RELU) {
#pragma unroll
        for (int m = 0; m < 8; ++m) r[m] = fmaxf(r[m], 0.f);
    }
    if (OUTF32) {
        float* Y = (float*)Yv;
        *(float4*)&Y[(long)i * M + j * 8]     = make_float4(r[0], r[1], r[2], r[3]);
        *(float4*)&Y[(long)i * M + j * 8 + 4] = make_float4(r[4], r[5], r[6], r[7]);
    } else {
        ushort* Y = (ushort*)Yv;
        uint4 o;
        o.x = (uint)f2b(r[0]) | ((uint)f2b(r[1]) << 16);
        o.y = (uint)f2b(r[2]) | ((uint)f2b(r[3]) << 16);
        o.z = (uint)f2b(r[4]) | ((uint)f2b(r[5]) << 16);
        o.w = (uint)f2b(r[6]) | ((uint)f2b(r[7]) << 16);
        *(uint4*)&Y[(long)i * M + j * 8] = o;
    }
}

extern "C" void kernel_launch(void* const* d_in, const int* in_sizes, int n_in,
                              void* d_out, int out_size, void* d_ws, size_t ws_size,
                              hipStream_t stream) {
    const float* x  = (const float*)d_in[0];
    const int*   ei = (const int*)d_in[1];
    const float* W1 = (const float*)d_in[2];
    const float* b1 = (const float*)d_in[3];
    const float* W2 = (const float*)d_in[4];
    const float* b2 = (const float*)d_in[5];
    float* out = (float*)d_out;

    const int n = in_sizes[0] / DI;   // 50000
    const int E = in_sizes[1] / 2;    // 800000
    const int* src = ei;
    const int* dst = ei + E;
    const int nb = (n + 255) / 256;
    const int np = nb * 256;

    // ws: deg/dinv[np] | off[np+256] | cursor[np] | bsum[256] | csr[E]
    //     | w1t[DH*DI] bf16 | w2t[DO*DH] bf16 | h0s[n*DH] bf16 | h[n*DH] bf16
    int*    deg    = (int*)d_ws;
    float*  dinv   = (float*)d_ws;
    int*    off    = deg + np;
    int*    cursor = off + np + 256;
    int*    bsum   = cursor + np;
    int*    csr    = bsum + 256;
    ushort* w1t    = (ushort*)(csr + E);
    ushort* w2t    = w1t + DH * DI;
    ushort* h0s    = w2t + DO * DH;
    ushort* h      = h0s + (size_t)n * DH;
    ushort* h1s    = h0s;             // reuse after gather1

    const int eb = (E + 255) / 256;

    hipMemsetAsync(deg, 0, (size_t)n * 4, stream);
    deg_count<<<eb, 256, 0, stream>>>(dst, deg, E);
    scan1<<<nb, 256, 0, stream>>>(deg, off, bsum, n);
    scan2<<<1, 256, 0, stream>>>(bsum, nb);
    scan3<<<nb, 256, 0, stream>>>(off, bsum, cursor, n, E);
    make_dinv<<<nb, 256, 0, stream>>>(deg, dinv, n);
    fill_csr<<<eb, 256, 0, stream>>>(src, dst, cursor, csr, E);
    wt_cvt<<<(DI * DH + 255) / 256, 256, 0, stream>>>(W1, w1t, DI, DH);
    wt_cvt<<<(DH * DO + 255) / 256, 256, 0, stream>>>(W2, w2t, DH, DO);

    const int gblk = (n + 63) / 64;
    // layer 1
    mfma_gemm<DI, DH, true><<<gblk, 256, 0, stream>>>(x, w1t, dinv, h0s, n);
    gather_fin<DH, true, false><<<(n + 15) / 16, 256, 0, stream>>>(off, csr, h0s, dinv, b1, h, n);
    // layer 2
    mfma_gemm<DH, DO, false><<<gblk, 256, 0, stream>>>(h, w2t, dinv, h1s, n);
    gather_fin<DO, false, true><<<(n + 31) / 32, 256, 0, stream>>>(off, csr, h1s, dinv, b2, out, n);
}